// Round 10
// baseline (313.230 us; speedup 1.0000x reference)
//
#include <hip/hip_runtime.h>

// ---------- types ----------
typedef unsigned short u16;
typedef __attribute__((ext_vector_type(4))) float f32x4;
typedef __attribute__((ext_vector_type(8))) short s16x8;
typedef __attribute__((ext_vector_type(8))) __bf16 bf16x8;
typedef __attribute__((ext_vector_type(4))) __bf16 bf16x4;
typedef __attribute__((ext_vector_type(4))) unsigned short u16x4;

#define LOG2E 1.44269504088896340736f

__device__ __forceinline__ u16 f2bf(float f) {
  unsigned u = __builtin_bit_cast(unsigned, f);
  u += 0x7fffu + ((u >> 16) & 1u);  // RNE
  return (u16)(u >> 16);
}

__device__ __forceinline__ f32x4 mfma16(s16x8 a, s16x8 b, f32x4 c) {
  return __builtin_amdgcn_mfma_f32_16x16x32_bf16(
      __builtin_bit_cast(bf16x8, a), __builtin_bit_cast(bf16x8, b), c, 0, 0, 0);
}

// XOR-swizzle mask for u16-indexed rows of 64 elems (128B): flips idx bits 3..5.
__device__ __forceinline__ int swzm(int row) {
  return (((row & 7) ^ ((row >> 3) & 7)) << 3);
}

// global -> LDS direct copy, 16B per lane. LDS dest must be uniform-base + lane*16.
#define GLOAD_LDS16(g, l)                                                      \
  __builtin_amdgcn_global_load_lds(                                            \
      (const __attribute__((address_space(1))) unsigned int*)(g),              \
      (__attribute__((address_space(3))) unsigned int*)(l), 16, 0, 0)

// ---------- fused prep: x cast + Wqkv transpose + Wp transpose ----------
// grid: [0,4096) cast | [4096,4864) wqkv | [4864,5120) wp
__global__ __launch_bounds__(256) void k_prep(const float* __restrict__ x,
                                              const float* __restrict__ Wq,
                                              const float* __restrict__ Wk,
                                              const float* __restrict__ Wv,
                                              const float* __restrict__ Wp,
                                              u16* __restrict__ Xb,
                                              u16* __restrict__ Wt,
                                              u16* __restrict__ WpT) {
  __shared__ float tile[64][65];
  const int bid = blockIdx.x;
  const int t = threadIdx.x;
  if (bid < 4096) {  // cast x -> bf16
    int i = (bid * 256 + t) * 4;
    float4 v = *(const float4*)(x + i);
    u16x4 o = {f2bf(v.x), f2bf(v.y), f2bf(v.z), f2bf(v.w)};
    *(u16x4*)(Xb + i) = o;
    return;
  }
  int rA = t >> 4, cA = (t & 15) * 4;
  if (bid < 4864) {  // Wq/Wk/Wv [H,C,D] -> Wt[qkv*1024+h*64+d][c]
    int idx = bid - 4096;
    int c0 = (idx & 15) * 64;
    int z = idx >> 4;           // 0..47
    int qkv = z >> 4, h = z & 15;
    const float* in = (qkv == 0 ? Wq : (qkv == 1 ? Wk : Wv)) + h * 1024 * 64;
#pragma unroll
    for (int rr = 0; rr < 4; ++rr) {
      int c = rr * 16 + rA;
      float4 v = *(const float4*)(in + (c0 + c) * 64 + cA);
      tile[c][cA] = v.x; tile[c][cA + 1] = v.y; tile[c][cA + 2] = v.z; tile[c][cA + 3] = v.w;
    }
    __syncthreads();
    int obase = qkv * 1024 + h * 64;
#pragma unroll
    for (int rr = 0; rr < 4; ++rr) {
      int d = rr * 16 + rA;
      u16x4 o = {f2bf(tile[cA][d]), f2bf(tile[cA + 1][d]), f2bf(tile[cA + 2][d]),
                 f2bf(tile[cA + 3][d])};
      *(u16x4*)(Wt + (obase + d) * 1024 + c0 + cA) = o;
    }
    return;
  }
  {  // Wp [1024][1024] -> WpT[n][k]
    int idx = bid - 4864;
    int r0 = (idx >> 4) * 64, c0 = (idx & 15) * 64;
#pragma unroll
    for (int rr = 0; rr < 4; ++rr) {
      int r = rr * 16 + rA;
      float4 v = *(const float4*)(Wp + (r0 + r) * 1024 + c0 + cA);
      tile[r][cA] = v.x; tile[r][cA + 1] = v.y; tile[r][cA + 2] = v.z; tile[r][cA + 3] = v.w;
    }
    __syncthreads();
#pragma unroll
    for (int rr = 0; rr < 4; ++rr) {
      int c = rr * 16 + rA;
      u16x4 o = {f2bf(tile[cA][c]), f2bf(tile[cA + 1][c]), f2bf(tile[cA + 2][c]),
                 f2bf(tile[cA + 3][c])};
      *(u16x4*)(WpT + (c0 + c) * 1024 + r0 + cA) = o;
    }
  }
}

// ---------- V-part of QKV -> Vtg[(b*16+h)*64+d][t] (global V^T) ----------
__global__ __launch_bounds__(256) void k_vt(const u16* __restrict__ QKV,
                                            u16* __restrict__ Vtg) {
  const int bh = blockIdx.y;  // b*16+h
  const int b = bh >> 4, h = bh & 15;
  const int t0 = blockIdx.x * 64;
  __shared__ u16 tile[64][65];
  const int tid = threadIdx.x;
  const int tr = tid >> 3, ch = tid & 7;
#pragma unroll
  for (int i = 0; i < 2; ++i) {
    int t = tr + i * 32;
    s16x8 v = *(const s16x8*)&QKV[(b * 2048 + t0 + t) * 3072 + 2048 + h * 64 + ch * 8];
#pragma unroll
    for (int j = 0; j < 8; ++j) tile[t][ch * 8 + j] = (u16)v[j];
  }
  __syncthreads();
#pragma unroll
  for (int i = 0; i < 2; ++i) {
    int d = tr + i * 32;
    s16x8 o;
#pragma unroll
    for (int j = 0; j < 8; ++j) o[j] = (short)tile[ch * 8 + j][d];
    *(s16x8*)&Vtg[(bh * 64 + d) * 2048 + t0 + ch * 8] = o;
  }
}

// ---------- GEMM: C[M,N] = A[M,K] @ Bt[N,K]^T  (bf16 in, f32 acc) ----------
// 128xBN tile, BK=64, 4 waves. 2-phase pipeline: stage(t+1) before compute(t).
template <int F32OUT, int BN>
__global__ __launch_bounds__(256) void gemm_bt(const u16* __restrict__ A,
                                               const u16* __restrict__ Bt,
                                               u16* __restrict__ Cb,
                                               float* __restrict__ Cf,
                                               const float* __restrict__ bias,
                                               int M, int N, int K) {
  constexpr int WRN = (BN == 128) ? 2 : 4;  // waves along M
  constexpr int WRS = 128 / WRN;            // wave row stride (64 or 32)
  constexpr int MB = WRS / 16;              // row frags per wave (4 or 2)
  __shared__ alignas(16) u16 As[2][128 * 64];
  __shared__ alignas(16) u16 Bs[2][BN * 64];
  const int tid = threadIdx.x;
  const int lane = tid & 63, w = tid >> 6;
  const int wr = (BN == 128) ? (w >> 1) : w;
  const int wc = (BN == 128) ? (w & 1) : 0;
  const int g = lane >> 4, c15 = lane & 15;
  const int nbk = N / BN;
  const int bm = blockIdx.x / nbk, bn = blockIdx.x % nbk;

  f32x4 acc[MB][4] = {};

  const int srow = tid >> 3;        // 0..31 (+ i*32)
  const u16* Ag = A + (bm * 128 + srow) * K + (tid & 7) * 8;
  const u16* Bg = Bt + (bn * BN + srow) * K + (tid & 7) * 8;
  const int lds_e = tid * 8;        // + i*2048

  auto stage = [&](int kt, int buf) {
#pragma unroll
    for (int i = 0; i < 4; ++i) GLOAD_LDS16(Ag + i * 32 * K + kt, &As[buf][lds_e + i * 2048]);
#pragma unroll
    for (int i = 0; i < BN / 32; ++i) GLOAD_LDS16(Bg + i * 32 * K + kt, &Bs[buf][lds_e + i * 2048]);
  };

  stage(0, 0);
  __syncthreads();

  const int nkt = K >> 6;
  for (int t = 0; t < nkt; ++t) {
    const int c = t & 1;
    if (t + 1 < nkt) stage((t + 1) << 6, c ^ 1);
#pragma unroll
    for (int kc = 0; kc < 2; ++kc) {
      s16x8 a[MB], b[4];
#pragma unroll
      for (int mb = 0; mb < MB; ++mb)
        a[mb] = *(const s16x8*)&As[c][(wr * WRS + mb * 16 + c15) * 64 + kc * 32 + g * 8];
#pragma unroll
      for (int nb = 0; nb < 4; ++nb)
        b[nb] = *(const s16x8*)&Bs[c][(wc * 64 + nb * 16 + c15) * 64 + kc * 32 + g * 8];
#pragma unroll
      for (int mb = 0; mb < MB; ++mb)
#pragma unroll
        for (int nb = 0; nb < 4; ++nb) acc[mb][nb] = mfma16(a[mb], b[nb], acc[mb][nb]);
    }
    __syncthreads();  // publishes buf c^1 (vmcnt drained here, hidden by compute)
  }
#pragma unroll
  for (int mb = 0; mb < MB; ++mb) {
#pragma unroll
    for (int nb = 0; nb < 4; ++nb) {
      int row0 = bm * 128 + wr * WRS + mb * 16 + g * 4;
      int col = bn * BN + wc * 64 + nb * 16 + c15;
#pragma unroll
      for (int r = 0; r < 4; ++r) {
        float v = acc[mb][nb][r];
        if (F32OUT)
          Cf[(row0 + r) * N + col] = v + bias[col];
        else
          Cb[(row0 + r) * N + col] = f2bf(v);
      }
    }
  }
}

// ---------- flash attention (KVBLK=128, V direct from L2) ----------
// QKV [4096][3072] bf16; Vtg [(b*16+h)*64+d][2048] bf16 (global V^T).
// AO: torch-raw-reshape: AO[(2h+b)*131072 + t*64 + d].
// Grid: 512 blocks x 512 threads (8 waves, 16 q-rows each = 128 q-rows/block).
// 16 iterations of 128 keys: halves barrier/vmcnt-drain events vs KVBLK=64.
// K staged via global_load_lds (dbuf, swizzled); V^T fragments loaded DIRECTLY
// from global (L2-resident) into registers per 64-key half, issued early so
// softmax covers the latency. LDS: Ks 32KB + Ps 16KB = 48KB.
__global__ __launch_bounds__(512, 4) void attn_fwd(const u16* __restrict__ QKV,
                                                   const u16* __restrict__ Vtg,
                                                   u16* __restrict__ AO) {
  __shared__ alignas(16) u16 Ks[2][128 * 64];  // [key][d] swizzled, dbuf
  __shared__ alignas(16) u16 Ps[8][16 * 64];   // per-wave P [q][64 keys] swizzled
  const int tid = threadIdx.x, lane = tid & 63, w = tid >> 6;
  const int bid = blockIdx.x;
  const int wgid = (bid & 7) * 64 + (bid >> 3);  // bijective XCD clustering
  const int qb = wgid & 15;        // 0..15 (128 q-rows each)
  const int bh = wgid >> 4;        // 0..31 (= 2h+b, AO order)
  const int h = bh >> 1, b = bh & 1;
  const int g = lane >> 4, c15 = lane & 15;
  const int bt0 = b * 2048;
  const float CS = 0.125f * LOG2E;  // scale folded with log2e

  // Q fragments: wave's rows = qb*128 + w*16 + c15
  s16x8 q[2];
#pragma unroll
  for (int kc = 0; kc < 2; ++kc) {
    int row = bt0 + qb * 128 + w * 16 + c15;
    q[kc] = *(const s16x8*)&QKV[row * 3072 + h * 64 + kc * 32 + g * 8];
  }

  f32x4 o[4] = {};
  float mrow = -1e30f, lrow = 0.f;  // per-lane q-row = c15; scaled domain

  // K staging: 512 threads x 2 x 16B = 16KB tile
  const int srow = tid >> 3;        // 0..63 (+ i*64)
  const int sch = tid & 7;
  auto stageK = [&](int key0, int buf) {
#pragma unroll
    for (int i = 0; i < 2; ++i) {
      int row = srow + i * 64;
      int s7 = (row & 7) ^ ((row >> 3) & 7);
      const u16* ks =
          QKV + (bt0 + key0 + row) * 3072 + 1024 + h * 64 + ((sch ^ s7) * 8);
      GLOAD_LDS16(ks, &Ks[buf][tid * 8 + i * 4096]);
    }
  };

  // V^T register loads: lane (g,c15) reads Vtg row db*16+c15, 16B chunk g
  const u16* Vbase = Vtg + ((b * 16 + h) * 64 + c15) * 2048 + g * 8;

  stageK(0, 0);
  __syncthreads();

  for (int t = 0; t < 16; ++t) {
    const int c = t & 1;
    const int key0 = t * 128;
    if (t < 15) stageK(key0 + 128, c ^ 1);

    // S^T = K Q^T: s[nb] lane holds S_raw[key=nb*16+g*4+r][q=c15], nb 0..7
    f32x4 s[8] = {};
    __builtin_amdgcn_s_setprio(1);
#pragma unroll
    for (int kc = 0; kc < 2; ++kc) {
      s16x8 kf[8];
#pragma unroll
      for (int nb = 0; nb < 8; ++nb) {
        int row = nb * 16 + c15;
        kf[nb] = *(const s16x8*)&Ks[c][row * 64 + ((kc * 32 + g * 8) ^ swzm(row))];
      }
#pragma unroll
      for (int nb = 0; nb < 8; ++nb) s[nb] = mfma16(kf[nb], q[kc], s[nb]);
    }
    __builtin_amdgcn_s_setprio(0);

    // issue V half-0 loads early (latency hidden under softmax)
    s16x8 vfA[2][4];
#pragma unroll
    for (int kcl = 0; kcl < 2; ++kcl)
#pragma unroll
      for (int db = 0; db < 4; ++db)
        vfA[kcl][db] =
            *(const s16x8*)(Vbase + db * 16 * 2048 + key0 + kcl * 32);

    // softmax over 128 keys (per lane: 32 in-lane + 2 shfl)
    float m0 = fmaxf(fmaxf(s[0][0], s[0][1]), fmaxf(s[0][2], s[0][3]));
    float m1 = fmaxf(fmaxf(s[1][0], s[1][1]), fmaxf(s[1][2], s[1][3]));
    float m2 = fmaxf(fmaxf(s[2][0], s[2][1]), fmaxf(s[2][2], s[2][3]));
    float m3 = fmaxf(fmaxf(s[3][0], s[3][1]), fmaxf(s[3][2], s[3][3]));
    float m4 = fmaxf(fmaxf(s[4][0], s[4][1]), fmaxf(s[4][2], s[4][3]));
    float m5 = fmaxf(fmaxf(s[5][0], s[5][1]), fmaxf(s[5][2], s[5][3]));
    float m6 = fmaxf(fmaxf(s[6][0], s[6][1]), fmaxf(s[6][2], s[6][3]));
    float m7 = fmaxf(fmaxf(s[7][0], s[7][1]), fmaxf(s[7][2], s[7][3]));
    float mr = fmaxf(fmaxf(fmaxf(m0, m1), fmaxf(m2, m3)),
                     fmaxf(fmaxf(m4, m5), fmaxf(m6, m7)));
    mr = fmaxf(mr, __shfl_xor(mr, 16, 64));
    mr = fmaxf(mr, __shfl_xor(mr, 32, 64));
    float m0s = mr * CS;
    if (__any(m0s > mrow + 8.0f)) {  // rescale (rare after warm-up)
      float mn = fmaxf(mrow, m0s);
      float alpha = exp2f(mrow - mn);
      mrow = mn;
      lrow *= alpha;
#pragma unroll
      for (int r = 0; r < 4; ++r) {
        float aB = __shfl(alpha, g * 4 + r, 64);  // c15-domain -> row-domain
#pragma unroll
        for (int db = 0; db < 4; ++db) o[db][r] *= aB;
      }
    }
    {
      float m = mrow;
#pragma unroll
      for (int nb = 0; nb < 8; ++nb)
#pragma unroll
        for (int r = 0; r < 4; ++r) s[nb][r] = exp2f(fmaf(s[nb][r], CS, -m));
      float a0 = (s[0][0] + s[0][1]) + (s[0][2] + s[0][3]);
      float a1 = (s[1][0] + s[1][1]) + (s[1][2] + s[1][3]);
      float a2 = (s[2][0] + s[2][1]) + (s[2][2] + s[2][3]);
      float a3 = (s[3][0] + s[3][1]) + (s[3][2] + s[3][3]);
      float a4 = (s[4][0] + s[4][1]) + (s[4][2] + s[4][3]);
      float a5 = (s[5][0] + s[5][1]) + (s[5][2] + s[5][3]);
      float a6 = (s[6][0] + s[6][1]) + (s[6][2] + s[6][3]);
      float a7 = (s[7][0] + s[7][1]) + (s[7][2] + s[7][3]);
      float rs = ((a0 + a1) + (a2 + a3)) + ((a4 + a5) + (a6 + a7));
      rs += __shfl_xor(rs, 16, 64);
      rs += __shfl_xor(rs, 32, 64);
      lrow += rs;
    }

    const int prow = c15;
    // ---- half 0: P write, PV with vfA ----
#pragma unroll
    for (int l = 0; l < 4; ++l) {
      bf16x4 pk = {(__bf16)s[l][0], (__bf16)s[l][1], (__bf16)s[l][2],
                   (__bf16)s[l][3]};
      *(bf16x4*)&Ps[w][prow * 64 + ((l * 16 + g * 4) ^ swzm(prow))] = pk;
    }
    __builtin_amdgcn_s_setprio(1);
#pragma unroll
    for (int kcl = 0; kcl < 2; ++kcl) {
      s16x8 pf =
          *(const s16x8*)&Ps[w][prow * 64 + ((kcl * 32 + g * 8) ^ swzm(prow))];
#pragma unroll
      for (int db = 0; db < 4; ++db) o[db] = mfma16(pf, vfA[kcl][db], o[db]);
    }
    __builtin_amdgcn_s_setprio(0);

    // ---- half 1: issue V loads, P write, PV ----
    s16x8 vfB[2][4];
#pragma unroll
    for (int kcl = 0; kcl < 2; ++kcl)
#pragma unroll
      for (int db = 0; db < 4; ++db)
        vfB[kcl][db] =
            *(const s16x8*)(Vbase + db * 16 * 2048 + key0 + 64 + kcl * 32);
#pragma unroll
    for (int l = 0; l < 4; ++l) {
      bf16x4 pk = {(__bf16)s[4 + l][0], (__bf16)s[4 + l][1], (__bf16)s[4 + l][2],
                   (__bf16)s[4 + l][3]};
      *(bf16x4*)&Ps[w][prow * 64 + ((l * 16 + g * 4) ^ swzm(prow))] = pk;
    }
    __builtin_amdgcn_s_setprio(1);
#pragma unroll
    for (int kcl = 0; kcl < 2; ++kcl) {
      s16x8 pf =
          *(const s16x8*)&Ps[w][prow * 64 + ((kcl * 32 + g * 8) ^ swzm(prow))];
#pragma unroll
      for (int db = 0; db < 4; ++db) o[db] = mfma16(pf, vfB[kcl][db], o[db]);
    }
    __builtin_amdgcn_s_setprio(0);

    __syncthreads();  // publishes Ks buf c^1 (vmcnt drain hidden by compute)
  }

  // epilogue: O / l (broadcast lrow c15-domain -> row-domain), torch-raw layout
#pragma unroll
  for (int r = 0; r < 4; ++r) {
    float lB = __shfl(lrow, g * 4 + r, 64);
    float rinv = 1.0f / lB;
    int trow = qb * 128 + w * 16 + g * 4 + r;
#pragma unroll
    for (int db = 0; db < 4; ++db)
      AO[(2 * h + b) * 131072 + trow * 64 + db * 16 + c15] =
          __builtin_bit_cast(u16, (__bf16)(o[db][r] * rinv));
  }
}

// ---------- launch ----------
extern "C" void kernel_launch(void* const* d_in, const int* in_sizes, int n_in,
                              void* d_out, int out_size, void* d_ws, size_t ws_size,
                              hipStream_t stream) {
  const float* x = (const float*)d_in[0];
  const float* Wq = (const float*)d_in[1];
  const float* Wk = (const float*)d_in[2];
  const float* Wv = (const float*)d_in[3];
  const float* Wp = (const float*)d_in[4];
  const float* bp = (const float*)d_in[5];
  float* out = (float*)d_out;

  u16* Xb = (u16*)d_ws;                   // [4096][1024]  (reused as Vtg later)
  u16* Wt = Xb + 4096 * 1024;             // [3072][1024]
  u16* WpT = Wt + 3072 * 1024;            // [1024][1024]
  u16* QKV = WpT + 1024 * 1024;           // [4096][3072]
  u16* AO = QKV + 4096 * 3072;            // [4096][1024]
  u16* Vtg = Xb;                          // [32*64][2048] — Xb dead after gemm1

  k_prep<<<5120, 256, 0, stream>>>(x, Wq, Wk, Wv, Wp, Xb, Wt, WpT);
  gemm_bt<0, 128><<<dim3(32 * 24), 256, 0, stream>>>(Xb, Wt, QKV, nullptr, nullptr, 4096, 3072, 1024);
  k_vt<<<dim3(32, 32), 256, 0, stream>>>(QKV, Vtg);
  attn_fwd<<<512, 512, 0, stream>>>(QKV, Vtg, AO);
  gemm_bt<1, 64><<<dim3(32 * 16), 256, 0, stream>>>(AO, WpT, nullptr, out, bp, 4096, 1024, 1024);
}